// Round 9
// baseline (166.421 us; speedup 1.0000x reference)
//
#include <hip/hip_runtime.h>
#include <hip/hip_bf16.h>
#include <math.h>

#define B_ 64
#define L_ 2048
#define V_ 50000
#define E_ 300
#define H_ 128
#define C_ 10
#define NGB 782            // 64-row tiles (4 x 16 per block)

// ws layout (bytes):
//     0: mm[2] (encoded min/max)      8: cnt[2] (done counters)
//    16: bitmap[1563] (6252 B)
//  8192: cArr[2048] f32   16384: pArr[2048] f32   24576: SArr[128] f32
// 65536: embW1 bf16 [50000][128] (12.8 MB)
// 12865536: psum f32 [64][64][128] (2 MB)
// 14962688: wmax f32 [64][4][128] (128 KB)

typedef short bf16x8 __attribute__((ext_vector_type(8)));
typedef float f32x4 __attribute__((ext_vector_type(4)));

__device__ __forceinline__ unsigned enc_f32(float f) {
  unsigned u = __float_as_uint(f);
  return (u & 0x80000000u) ? ~u : (u | 0x80000000u);
}
__device__ __forceinline__ float dec_f32(unsigned u) {
  unsigned v = (u & 0x80000000u) ? (u ^ 0x80000000u) : ~u;
  return __uint_as_float(v);
}
__device__ __forceinline__ unsigned short f2bf(float f) {  // RNE f32->bf16
  unsigned u = __float_as_uint(f);
  unsigned r = 0x7FFFu + ((u >> 16) & 1u);
  return (unsigned short)((u + r) >> 16);
}

// ---- K0: init mm + counters + zero bitmap ----
__global__ __launch_bounds__(512) void k_init(unsigned* __restrict__ mm,
                                              unsigned* __restrict__ cnt,
                                              unsigned* __restrict__ bm) {
  const int t = threadIdx.x;
  if (t == 0) { mm[0] = 0xFFFFFFFFu; mm[1] = 0u; cnt[0] = 0u; cnt[1] = 0u; }
  for (int i = t; i < 1563; i += 512) bm[i] = 0u;
}

// ---- K1: presence bitmap ----
__global__ __launch_bounds__(256) void k_bitmap(const int* __restrict__ x,
                                                unsigned* __restrict__ bm) {
  const int i = blockIdx.x * 256 + threadIdx.x;
  const int v = x[i];
  atomicOr(&bm[v >> 5], 1u << (v & 31));
}

// ---- K2: embW1 = bf16(emb @ W1), fragment-direct global loads.
// No LDS, no barriers. 4 waves/block; wave wv owns H-cols [wv*32, wv*32+32)
// (2 A-frags of W1, register-resident). B-frags load straight from emb in
// MFMA layout: lane -> row (lane&15), 8 consecutive k at (lane>>4)*8 — 4
// lanes/row -> full 64B-line consumption; 4 waves share the 16-row window
// via L1. 3-deep kt pipeline, statically rotated. Wave 0 folds the
// presence-filtered min/max. Last-finishing block runs the Newton scan. ----
__global__ __launch_bounds__(256) void k_gemm(
    const float* __restrict__ emb, const float* __restrict__ W1,
    const unsigned* __restrict__ bm, unsigned* __restrict__ mm,
    unsigned short* __restrict__ embW1, unsigned* __restrict__ cnt,
    const float* __restrict__ alphaP, const float* __restrict__ betaP,
    float* __restrict__ cArr, float* __restrict__ pArr,
    float* __restrict__ SArr) {
  __shared__ bool lastf;
  const int bid = blockIdx.x;
  const int tid = threadIdx.x;
  const int wv = tid >> 6, lane = tid & 63;
  const int arow = lane & 15, g = lane >> 4;

  // A-fragments: W1, m = H col, k = kt*32 + g*8 + i (zero-padded K)
  bf16x8 afr[2][10];
#pragma unroll
  for (int f = 0; f < 2; ++f) {
    const int col = wv * 32 + f * 16 + arow;
#pragma unroll
    for (int kt = 0; kt < 10; ++kt)
#pragma unroll
      for (int i = 0; i < 8; ++i) {
        const int k = kt * 32 + g * 8 + i;
        afr[f][kt][i] = (short)((k < E_) ? f2bf(W1[k * H_ + col]) : 0);
      }
  }

  float mn = 3.4e38f, mx = -3.4e38f;

#pragma unroll
  for (int t = 0; t < 4; ++t) {
    const int row = bid * 64 + t * 16 + arow;
    const int rowc = (row < V_) ? row : (V_ - 1);
    const float* rp = emb + (size_t)rowc * E_;
    const bool pres = (wv == 0) && (row < V_) &&
                      ((bm[row >> 5] >> (row & 31)) & 1u);
    float4 pa[3], pb[3];
#pragma unroll
    for (int p = 0; p < 3; ++p) {                 // prologue kt=0..2 (k<=103)
      pa[p] = *(const float4*)(rp + p * 32 + g * 8);
      pb[p] = *(const float4*)(rp + p * 32 + g * 8 + 4);
    }
    f32x4 acc0 = {0, 0, 0, 0}, acc1 = {0, 0, 0, 0};
#pragma unroll
    for (int kt = 0; kt < 10; ++kt) {
      const float4 lo = pa[kt % 3], h4 = pb[kt % 3];
      if (kt + 3 < 10) {                          // prefetch kt+3 (static slot)
        const int c = (kt + 3) * 32 + g * 8;
        pa[kt % 3] = *(const float4*)(rp + c);
        int c2 = c + 4;
        if (c2 > 296) c2 = 296;                   // kt=9,g=1: clamp (A=0 there)
        pb[kt % 3] = *(const float4*)(rp + c2);
      }
      if (pres) {                                 // lo k<=299 always valid
        mn = fminf(mn, fminf(fminf(lo.x, lo.y), fminf(lo.z, lo.w)));
        mx = fmaxf(mx, fmaxf(fmaxf(lo.x, lo.y), fmaxf(lo.z, lo.w)));
        if (!(kt == 9 && g == 1)) {               // h4 k>=300 excluded
          mn = fminf(mn, fminf(fminf(h4.x, h4.y), fminf(h4.z, h4.w)));
          mx = fmaxf(mx, fmaxf(fmaxf(h4.x, h4.y), fmaxf(h4.z, h4.w)));
        }
      }
      bf16x8 bb;
      bb[0] = (short)f2bf(lo.x); bb[1] = (short)f2bf(lo.y);
      bb[2] = (short)f2bf(lo.z); bb[3] = (short)f2bf(lo.w);
      bb[4] = (short)f2bf(h4.x); bb[5] = (short)f2bf(h4.y);
      bb[6] = (short)f2bf(h4.z); bb[7] = (short)f2bf(h4.w);
      acc0 = __builtin_amdgcn_mfma_f32_16x16x32_bf16(afr[0][kt], bb, acc0, 0, 0, 0);
      acc1 = __builtin_amdgcn_mfma_f32_16x16x32_bf16(afr[1][kt], bb, acc1, 0, 0, 0);
    }
    if (row < V_) {                               // D: n=arow(emb row), m=H col
      unsigned long long p0 = (unsigned long long)f2bf(acc0[0])
                            | ((unsigned long long)f2bf(acc0[1]) << 16)
                            | ((unsigned long long)f2bf(acc0[2]) << 32)
                            | ((unsigned long long)f2bf(acc0[3]) << 48);
      unsigned long long p1 = (unsigned long long)f2bf(acc1[0])
                            | ((unsigned long long)f2bf(acc1[1]) << 16)
                            | ((unsigned long long)f2bf(acc1[2]) << 32)
                            | ((unsigned long long)f2bf(acc1[3]) << 48);
      *(unsigned long long*)&embW1[(size_t)row * H_ + wv * 32 + g * 4] = p0;
      *(unsigned long long*)&embW1[(size_t)row * H_ + wv * 32 + 16 + g * 4] = p1;
    }
  }

  // ---- wave-0 min/max -> atomics; done-counter; last block runs scan ----
  if (wv == 0) {
#pragma unroll
    for (int s = 1; s < 64; s <<= 1) {
      mn = fminf(mn, __shfl_xor(mn, s));
      mx = fmaxf(mx, __shfl_xor(mx, s));
    }
    if (lane == 0) {
      atomicMin(&mm[0], enc_f32(mn));
      atomicMax(&mm[1], enc_f32(mx));
      __threadfence();
      lastf = (atomicAdd(&cnt[0], 1u) == NGB - 1u);
    }
  }
  __syncthreads();
  if (!lastf) return;

  // ===== fused Newton scan for c_t, P_t (tid<64) + SArr (tid 64..191) =====
  if (tid < 64) {
    const int ln = tid;
    const float alpha = alphaP[0];
    const float lmn = dec_f32(atomicOr(&mm[0], 0u));
    const float lmx = dec_f32(atomicOr(&mm[1], 0u));
    const float sb = betaP[0] * lmn / (lmx - lmn);   // -beta*xn(xe=0)
    const float tl = (float)(ln * 32);

    float c = sqrtf(fmaf(2.0f * alpha, tl, 1.0f));
    if (fabsf(sb) > 1e-7f) {
      const float isb = 1.0f / sb;
      const float k2 = alpha * isb * isb;
      const float d0 = fmaxf(alpha + sb, 1e-8f);
#pragma unroll
      for (int it = 0; it < 4; ++it) {
        const float den = fmaxf(fmaf(sb, c, alpha), 1e-8f);
        const float T = (c - 1.0f) * isb - k2 * logf(den / d0);
        c = c - (T - tl) * den / c;
        c = fminf(fmaxf(c, 1.0f), 1e3f);
      }
    }
    if (ln == 0) c = 1.0f;

#pragma unroll
    for (int sw = 0; sw < 3; ++sw) {
      float cc = c, d = 1.0f;
#pragma unroll
      for (int j = 0; j < 32; ++j) {
        const float r = __builtin_amdgcn_rcpf(cc);
        d *= fmaf(-alpha * r, r, 1.0f);
        cc = fmaf(alpha, r, cc) + sb;
      }
      float A = d, Bv = fmaf(-d, c, cc);
#pragma unroll
      for (int o = 1; o < 64; o <<= 1) {
        const float A2 = __shfl_up(A, o);
        const float B2 = __shfl_up(Bv, o);
        if (ln >= o) { Bv = fmaf(A, B2, Bv); A *= A2; }
      }
      const float As = __shfl_up(A, 1);
      const float Bs = __shfl_up(Bv, 1);
      if (ln > 0) c = As + Bs;
    }

    float av[32];
    float cc = c, Q = 1.0f;
#pragma unroll
    for (int j = 0; j < 32; ++j) {
      cArr[ln * 32 + j] = cc;
      const float r = __builtin_amdgcn_rcpf(cc);
      const float a = fmaf(-alpha * r, r, 1.0f);
      av[j] = a; Q *= a;
      cc = fmaf(alpha, r, cc) + sb;
    }
    float Pp = Q;
#pragma unroll
    for (int o = 1; o < 64; o <<= 1) {
      const float q2 = __shfl_up(Pp, o);
      if (ln >= o) Pp *= q2;
    }
    const float Ps = __shfl_up(Pp, 1);
    float P = (ln == 0) ? 1.0f : Ps;
#pragma unroll
    for (int j = 0; j < 32; ++j) {
      pArr[ln * 32 + j] = P;
      P *= av[j];
    }
  } else if (tid < 192) {
    const int cl = tid - 64;
    float s = 0.0f;
    for (int k = 0; k < E_; ++k) s += W1[k * H_ + cl];
    SArr[cl] = s;
  }
}

// ---- K3: per-(b, 32-step segment) partial sums of q_s * y_s ----
__global__ __launch_bounds__(256) void k_psum(const int* __restrict__ x,
                                              const unsigned short* __restrict__ embW1,
                                              const float* __restrict__ pArr,
                                              float* __restrict__ psum) {
  const int bid = blockIdx.x;             // 1024 blocks
  const int b = bid >> 4, sq = bid & 15;
  const int wv = threadIdx.x >> 6, lane = threadIdx.x & 63;
  const int v = sq * 4 + wv;              // 0..63
  const int t0 = v * 32;
  const int col2 = lane * 2;
  float s0 = 0.f, s1 = 0.f;
#pragma unroll 8
  for (int j = 0; j < 32; ++j) {
    const int t = t0 + j;
    const int tok = x[b * L_ + t];
    const float q = (t + 1 < L_) ? __builtin_amdgcn_rcpf(pArr[t + 1]) : 0.0f;
    const unsigned y2 = *(const unsigned*)(embW1 + (size_t)tok * H_ + col2);
    s0 = fmaf(q, __uint_as_float(y2 << 16), s0);
    s1 = fmaf(q, __uint_as_float(y2 & 0xFFFF0000u), s1);
  }
  float* p = psum + (size_t)(b * 64 + v) * H_ + col2;
  p[0] = s0; p[1] = s1;
}

// ---- K4: z-max per (b, quarter); last block fuses tanh + W2 matvec ----
__global__ __launch_bounds__(1024) void k_zmax(
    const int* __restrict__ x, const unsigned short* __restrict__ embW1,
    const float* __restrict__ cArr, const float* __restrict__ pArr,
    const float* __restrict__ SArr, const float* __restrict__ psum,
    const float* __restrict__ betaP, const unsigned* __restrict__ mm,
    float* __restrict__ wmax, unsigned* __restrict__ cnt,
    const float* __restrict__ b1, const float* __restrict__ W2,
    const float* __restrict__ b2, float* __restrict__ out) {
  __shared__ float zsh[16][128];
  __shared__ float psh[64][128];
  __shared__ bool lastf;
  const int bid = blockIdx.x;             // 256 blocks
  const int b = bid >> 2, qt = bid & 3;
  const int wv = threadIdx.x >> 6, lane = threadIdx.x & 63;
  const int v = qt * 16 + wv;             // 0..63
  const int t0 = v * 32;
  const int col2 = lane * 2;
  const float mn = dec_f32(mm[0]), mx = dec_f32(mm[1]);
  const float binv = betaP[0] / (mx - mn);
  const float S0 = SArr[col2], S1 = SArr[col2 + 1];

  float m0 = 0.f, m1 = 0.f;               // prefix m at t0 from psum
  for (int u = 0; u < v; ++u) {
    const float* p = psum + (size_t)(b * 64 + u) * H_ + col2;
    m0 += p[0]; m1 += p[1];
  }
  float z0m = -3.4e38f, z1m = -3.4e38f;
#pragma unroll 4
  for (int j = 0; j < 32; ++j) {
    const int t = t0 + j;
    const int tok = x[b * L_ + t];
    const unsigned y2 = *(const unsigned*)(embW1 + (size_t)tok * H_ + col2);
    const float ct = cArr[t];
    const float gt = binv * pArr[t];
    const float q = (t + 1 < L_) ? __builtin_amdgcn_rcpf(pArr[t + 1]) : 0.0f;
    z0m = fmaxf(z0m, fmaf(-gt, m0, ct * S0));   // z uses m BEFORE adding term t
    z1m = fmaxf(z1m, fmaf(-gt, m1, ct * S1));
    m0 = fmaf(q, __uint_as_float(y2 << 16), m0);
    m1 = fmaf(q, __uint_as_float(y2 & 0xFFFF0000u), m1);
  }
  zsh[wv][col2] = z0m; zsh[wv][col2 + 1] = z1m;
  __syncthreads();
  if (threadIdx.x < 128) {
    float mz = zsh[0][threadIdx.x];
#pragma unroll
    for (int w2 = 1; w2 < 16; ++w2) mz = fmaxf(mz, zsh[w2][threadIdx.x]);
    wmax[(b * 4 + qt) * H_ + threadIdx.x] = mz;
    __threadfence();
  }
  __syncthreads();
  if (threadIdx.x == 0) lastf = (atomicAdd(&cnt[1], 1u) == 255u);
  __syncthreads();
  if (!lastf) return;

  // ===== fused tail: pooled = tanh(max_q wmax + b1); out = pooled@W2 + b2 =====
  __threadfence();
  for (int idx = threadIdx.x; idx < B_ * H_; idx += 1024) {
    const int bb = idx >> 7, h = idx & 127;
    float mz = wmax[(bb * 4) * H_ + h];
#pragma unroll
    for (int q2 = 1; q2 < 4; ++q2) mz = fmaxf(mz, wmax[(bb * 4 + q2) * H_ + h]);
    psh[bb][h] = tanhf(mz + b1[h]);
  }
  __syncthreads();
  if (threadIdx.x < B_ * C_) {
    const int bb = threadIdx.x / C_, c = threadIdx.x % C_;
    float s = b2[c];
#pragma unroll 8
    for (int k = 0; k < H_; ++k) s = fmaf(psh[bb][k], W2[k * C_ + c], s);
    out[threadIdx.x] = s;
  }
}

extern "C" void kernel_launch(void* const* d_in, const int* in_sizes, int n_in,
                              void* d_out, int out_size, void* d_ws, size_t ws_size,
                              hipStream_t stream) {
  const int* x = (const int*)d_in[0];
  const float* emb = (const float*)d_in[1];
  const float* alpha = (const float*)d_in[2];
  const float* beta = (const float*)d_in[3];
  const float* W1 = (const float*)d_in[4];
  const float* b1 = (const float*)d_in[5];
  const float* W2 = (const float*)d_in[6];
  const float* b2 = (const float*)d_in[7];
  (void)in_sizes; (void)n_in; (void)out_size; (void)ws_size;

  char* ws = (char*)d_ws;
  unsigned* mm = (unsigned*)ws;
  unsigned* cnt = (unsigned*)(ws + 8);
  unsigned* bm = (unsigned*)(ws + 16);
  float* cArr = (float*)(ws + 8192);
  float* pArr = (float*)(ws + 16384);
  float* SArr = (float*)(ws + 24576);
  unsigned short* embW1 = (unsigned short*)(ws + 65536);
  float* psum = (float*)(ws + 12865536);
  float* wmax = (float*)(ws + 14962688);

  k_init<<<1, 512, 0, stream>>>(mm, cnt, bm);
  k_bitmap<<<(B_ * L_) / 256, 256, 0, stream>>>(x, bm);
  k_gemm<<<NGB, 256, 0, stream>>>(emb, W1, bm, mm, embW1, cnt,
                                  alpha, beta, cArr, pArr, SArr);
  k_psum<<<1024, 256, 0, stream>>>(x, embW1, pArr, psum);
  k_zmax<<<256, 1024, 0, stream>>>(x, embW1, cArr, pArr, SArr, psum, beta, mm,
                                   wmax, cnt, b1, W2, b2, (float*)d_out);
}

// Round 10
// 129.602 us; speedup vs baseline: 1.2841x; 1.2841x over previous
//
#include <hip/hip_runtime.h>
#include <hip/hip_bf16.h>
#include <math.h>

#define B_ 64
#define L_ 2048
#define V_ 50000
#define E_ 300
#define H_ 128
#define C_ 10
#define NGB 782            // 64-row tiles (2 subtiles of 32)

// ws layout (bytes):
//     0: mm[2] (encoded min/max)      8: cnt[2] (done counters)
//    16: bitmap[1563] (6252 B)
//  8192: cArr[2048] f32   16384: pArr[2048] f32   24576: SArr[128] f32
// 65536: embW1 bf16 [50000][128] (12.8 MB)
// 12865536: psum f32 [64][64][128] (2 MB)
// 14962688: wmax f32 [64][4][128] (128 KB)

typedef short bf16x8 __attribute__((ext_vector_type(8)));
typedef float f32x4 __attribute__((ext_vector_type(4)));

__device__ __forceinline__ unsigned enc_f32(float f) {
  unsigned u = __float_as_uint(f);
  return (u & 0x80000000u) ? ~u : (u | 0x80000000u);
}
__device__ __forceinline__ float dec_f32(unsigned u) {
  unsigned v = (u & 0x80000000u) ? (u ^ 0x80000000u) : ~u;
  return __uint_as_float(v);
}
__device__ __forceinline__ unsigned short f2bf(float f) {  // RNE f32->bf16
  unsigned u = __float_as_uint(f);
  unsigned r = 0x7FFFu + ((u >> 16) & 1u);
  return (unsigned short)((u + r) >> 16);
}

// ---- K0: init mm + counters + zero bitmap ----
__global__ __launch_bounds__(512) void k_init(unsigned* __restrict__ mm,
                                              unsigned* __restrict__ cnt,
                                              unsigned* __restrict__ bm) {
  const int t = threadIdx.x;
  if (t == 0) { mm[0] = 0xFFFFFFFFu; mm[1] = 0u; cnt[0] = 0u; cnt[1] = 0u; }
  for (int i = t; i < 1563; i += 512) bm[i] = 0u;
}

// ---- K1: presence bitmap ----
__global__ __launch_bounds__(256) void k_bitmap(const int* __restrict__ x,
                                                unsigned* __restrict__ bm) {
  const int i = blockIdx.x * 256 + threadIdx.x;
  const int v = x[i];
  atomicOr(&bm[v >> 5], 1u << (v & 31));
}

// ---- K2: embW1 = bf16(emb @ W1) + presence min/max (round-4 structure:
// 782 blocks x 512 thr, 64 rows as 2 subtiles of 32, async reg->LDS split).
// Last-finishing block runs the parallel Newton scan + SArr. ----
__global__ __launch_bounds__(512) void k_gemm(
    const float* __restrict__ emb, const float* __restrict__ W1,
    const unsigned* __restrict__ bm, unsigned* __restrict__ mm,
    unsigned short* __restrict__ embW1, unsigned* __restrict__ cnt,
    const float* __restrict__ alphaP, const float* __restrict__ betaP,
    float* __restrict__ cArr, float* __restrict__ pArr,
    float* __restrict__ SArr) {
  __shared__ unsigned short at[32][328];   // bf16 subtile, 20,992 B
  __shared__ float smn[8], smx[8];
  __shared__ bool lastf;
  const int r0 = blockIdx.x * 64;
  const int tid = threadIdx.x;
  const int w = tid >> 6;
  const int lane = tid & 63;
  const int arow = lane & 15;
  const int g = lane >> 4;
  const int rr = tid >> 4;          // staging: row 0..31, 16 thr/row
  const int c16 = tid & 15;

  float mn = 3.4e38f, mx = -3.4e38f;

  // ---- issue subtile-0 loads ----
  float4 pf[5];
  {
    const int row = r0 + rr;
    const float* rp = emb + (size_t)((row < V_) ? row : (V_ - 1)) * E_;
#pragma unroll
    for (int j = 0; j < 5; ++j) {
      const int k0 = c16 * 4 + 64 * j;
      pf[j] = (k0 < E_) ? *(const float4*)(rp + k0) : float4{0, 0, 0, 0};
    }
  }

  // ---- A-fragments: W1^T, m-dim = H col, k = 32kt + 8g + i ----
  bf16x8 bfr[10];
  const int col = w * 16 + arow;
#pragma unroll
  for (int kt = 0; kt < 10; ++kt) {
    const int k0 = kt * 32 + g * 8;
#pragma unroll
    for (int i = 0; i < 8; ++i) {
      const int k = k0 + i;
      bfr[kt][i] = (short)((k < E_) ? f2bf(W1[k * H_ + col]) : 0);
    }
  }

#pragma unroll
  for (int st = 0; st < 2; ++st) {
    const int row = r0 + st * 32 + rr;
    const bool pres = (row < V_) && ((bm[row >> 5] >> (row & 31)) & 1u);
#pragma unroll
    for (int j = 0; j < 5; ++j) {
      const int k0 = c16 * 4 + 64 * j;
      if (k0 < 320) {
        const float4 v = pf[j];
        if (pres && k0 < E_) {
          mn = fminf(mn, fminf(fminf(v.x, v.y), fminf(v.z, v.w)));
          mx = fmaxf(mx, fmaxf(fmaxf(v.x, v.y), fmaxf(v.z, v.w)));
        }
        unsigned long long p = 0ull;
        if (k0 < E_)
          p = (unsigned long long)f2bf(v.x) | ((unsigned long long)f2bf(v.y) << 16)
            | ((unsigned long long)f2bf(v.z) << 32) | ((unsigned long long)f2bf(v.w) << 48);
        *(unsigned long long*)&at[rr][k0] = p;
      }
    }
    if (st == 0) {                       // issue subtile-1 loads now
      const int row1 = r0 + 32 + rr;
      const float* rp = emb + (size_t)((row1 < V_) ? row1 : (V_ - 1)) * E_;
#pragma unroll
      for (int j = 0; j < 5; ++j) {
        const int k0 = c16 * 4 + 64 * j;
        pf[j] = (k0 < E_) ? *(const float4*)(rp + k0) : float4{0, 0, 0, 0};
      }
    }
    __syncthreads();                     // subtile st staged
#pragma unroll
    for (int rt = 0; rt < 2; ++rt) {
      f32x4 acc = {0, 0, 0, 0};
#pragma unroll
      for (int kt = 0; kt < 10; ++kt) {
        bf16x8 bb = *(const bf16x8*)&at[rt * 16 + arow][kt * 32 + g * 8];
        acc = __builtin_amdgcn_mfma_f32_16x16x32_bf16(bfr[kt], bb, acc, 0, 0, 0);
      }
      const int grow = r0 + st * 32 + rt * 16 + arow;
      if (grow < V_) {
        unsigned long long p = (unsigned long long)f2bf(acc[0])
                             | ((unsigned long long)f2bf(acc[1]) << 16)
                             | ((unsigned long long)f2bf(acc[2]) << 32)
                             | ((unsigned long long)f2bf(acc[3]) << 48);
        *(unsigned long long*)&embW1[(size_t)grow * H_ + w * 16 + g * 4] = p;
      }
    }
    __syncthreads();                     // reads done before re-staging LDS
  }

  // ---- block min/max -> atomics; done-counter; last block runs scan ----
#pragma unroll
  for (int s = 1; s < 64; s <<= 1) {
    mn = fminf(mn, __shfl_xor(mn, s));
    mx = fmaxf(mx, __shfl_xor(mx, s));
  }
  if (lane == 0) { smn[w] = mn; smx[w] = mx; }
  __syncthreads();
  if (tid == 0) {
#pragma unroll
    for (int i = 1; i < 8; ++i) { mn = fminf(mn, smn[i]); mx = fmaxf(mx, smx[i]); }
    atomicMin(&mm[0], enc_f32(mn));
    atomicMax(&mm[1], enc_f32(mx));
    __threadfence();
    lastf = (atomicAdd(&cnt[0], 1u) == NGB - 1u);
  }
  __syncthreads();
  if (!lastf) return;

  // ===== fused Newton scan for c_t, P_t (tid<64) + SArr (tid 64..191) =====
  if (tid < 64) {
    const int ln = tid;
    const float alpha = alphaP[0];
    const float lmn = dec_f32(atomicOr(&mm[0], 0u));
    const float lmx = dec_f32(atomicOr(&mm[1], 0u));
    const float sb = betaP[0] * lmn / (lmx - lmn);   // -beta*xn(xe=0)
    const float tl = (float)(ln * 32);

    float c = sqrtf(fmaf(2.0f * alpha, tl, 1.0f));
    if (fabsf(sb) > 1e-7f) {
      const float isb = 1.0f / sb;
      const float k2 = alpha * isb * isb;
      const float d0 = fmaxf(alpha + sb, 1e-8f);
#pragma unroll
      for (int it = 0; it < 4; ++it) {
        const float den = fmaxf(fmaf(sb, c, alpha), 1e-8f);
        const float T = (c - 1.0f) * isb - k2 * logf(den / d0);
        c = c - (T - tl) * den / c;
        c = fminf(fmaxf(c, 1.0f), 1e3f);
      }
    }
    if (ln == 0) c = 1.0f;

#pragma unroll
    for (int sw = 0; sw < 3; ++sw) {
      float cc = c, d = 1.0f;
#pragma unroll
      for (int j = 0; j < 32; ++j) {
        const float r = __builtin_amdgcn_rcpf(cc);
        d *= fmaf(-alpha * r, r, 1.0f);
        cc = fmaf(alpha, r, cc) + sb;
      }
      float A = d, Bv = fmaf(-d, c, cc);
#pragma unroll
      for (int o = 1; o < 64; o <<= 1) {
        const float A2 = __shfl_up(A, o);
        const float B2 = __shfl_up(Bv, o);
        if (ln >= o) { Bv = fmaf(A, B2, Bv); A *= A2; }
      }
      const float As = __shfl_up(A, 1);
      const float Bs = __shfl_up(Bv, 1);
      if (ln > 0) c = As + Bs;
    }

    float av[32];
    float cc = c, Q = 1.0f;
#pragma unroll
    for (int j = 0; j < 32; ++j) {
      cArr[ln * 32 + j] = cc;
      const float r = __builtin_amdgcn_rcpf(cc);
      const float a = fmaf(-alpha * r, r, 1.0f);
      av[j] = a; Q *= a;
      cc = fmaf(alpha, r, cc) + sb;
    }
    float Pp = Q;
#pragma unroll
    for (int o = 1; o < 64; o <<= 1) {
      const float q2 = __shfl_up(Pp, o);
      if (ln >= o) Pp *= q2;
    }
    const float Ps = __shfl_up(Pp, 1);
    float P = (ln == 0) ? 1.0f : Ps;
#pragma unroll
    for (int j = 0; j < 32; ++j) {
      pArr[ln * 32 + j] = P;
      P *= av[j];
    }
  } else if (tid < 192) {
    const int cl = tid - 64;
    float s = 0.0f;
    for (int k = 0; k < E_; ++k) s += W1[k * H_ + cl];
    SArr[cl] = s;
  }
}

// ---- K3: per-(b, 32-step segment) partial sums. tok/q preloaded into
// lanes 0-31, per-step via __shfl -> all 32 row-gathers independent. ----
__global__ __launch_bounds__(256) void k_psum(const int* __restrict__ x,
                                              const unsigned short* __restrict__ embW1,
                                              const float* __restrict__ pArr,
                                              float* __restrict__ psum) {
  const int bid = blockIdx.x;             // 1024 blocks
  const int b = bid >> 4, sq = bid & 15;
  const int wv = threadIdx.x >> 6, lane = threadIdx.x & 63;
  const int v = sq * 4 + wv;              // 0..63
  const int t0 = v * 32;
  const int col2 = lane * 2;
  int tokv = 0; float qv = 0.0f;
  if (lane < 32) {
    const int t = t0 + lane;
    tokv = x[b * L_ + t];
    qv = (t + 1 < L_) ? __builtin_amdgcn_rcpf(pArr[t + 1]) : 0.0f;
  }
  float s0 = 0.f, s1 = 0.f;
#pragma unroll
  for (int j = 0; j < 32; ++j) {
    const int tok = __shfl(tokv, j);
    const float q = __shfl(qv, j);
    const unsigned y2 = *(const unsigned*)(embW1 + (size_t)tok * H_ + col2);
    s0 = fmaf(q, __uint_as_float(y2 << 16), s0);
    s1 = fmaf(q, __uint_as_float(y2 & 0xFFFF0000u), s1);
  }
  float* p = psum + (size_t)(b * 64 + v) * H_ + col2;
  p[0] = s0; p[1] = s1;
}

// ---- K4: z-max per (b, quarter). psum cached in LDS (prefix = LDS reads);
// tok/c/P/q preloaded + __shfl; last block fuses tanh + W2 matvec. ----
__global__ __launch_bounds__(1024) void k_zmax(
    const int* __restrict__ x, const unsigned short* __restrict__ embW1,
    const float* __restrict__ cArr, const float* __restrict__ pArr,
    const float* __restrict__ SArr, const float* __restrict__ psum,
    const float* __restrict__ betaP, const unsigned* __restrict__ mm,
    float* __restrict__ wmax, unsigned* __restrict__ cnt,
    const float* __restrict__ b1, const float* __restrict__ W2,
    const float* __restrict__ b2, float* __restrict__ out) {
  __shared__ float ps[64][128];           // psum cache; reused as pooled staging
  __shared__ float zsh[16][128];
  __shared__ bool lastf;
  const int bid = blockIdx.x;             // 256 blocks
  const int b = bid >> 2, qt = bid & 3;
  const int tid = threadIdx.x;
  const int wv = tid >> 6, lane = tid & 63;
  const int v = qt * 16 + wv;             // 0..63
  const int t0 = v * 32;
  const int col2 = lane * 2;

  for (int i = tid; i < 64 * 128; i += 1024)      // cache psum[b][*][*]
    ps[i >> 7][i & 127] = psum[(size_t)(b * 64) * H_ + i];

  int tokv = 0; float qv = 0.f, cv = 0.f, pv = 0.f;
  if (lane < 32) {
    const int t = t0 + lane;
    tokv = x[b * L_ + t];
    cv = cArr[t];
    pv = pArr[t];
    qv = (t + 1 < L_) ? __builtin_amdgcn_rcpf(pArr[t + 1]) : 0.0f;
  }
  const float mn = dec_f32(mm[0]), mx = dec_f32(mm[1]);
  const float binv = betaP[0] / (mx - mn);
  const float S0 = SArr[col2], S1 = SArr[col2 + 1];
  __syncthreads();

  float m0 = 0.f, m1 = 0.f;               // prefix m at t0 from LDS
  for (int u = 0; u < v; ++u) { m0 += ps[u][col2]; m1 += ps[u][col2 + 1]; }

  float z0m = -3.4e38f, z1m = -3.4e38f;
#pragma unroll
  for (int j = 0; j < 32; ++j) {
    const int tok = __shfl(tokv, j);
    const float ct = __shfl(cv, j);
    const float gt = binv * __shfl(pv, j);
    const float q = __shfl(qv, j);
    const unsigned y2 = *(const unsigned*)(embW1 + (size_t)tok * H_ + col2);
    z0m = fmaxf(z0m, fmaf(-gt, m0, ct * S0));   // z uses m BEFORE adding term t
    z1m = fmaxf(z1m, fmaf(-gt, m1, ct * S1));
    m0 = fmaf(q, __uint_as_float(y2 << 16), m0);
    m1 = fmaf(q, __uint_as_float(y2 & 0xFFFF0000u), m1);
  }
  zsh[wv][col2] = z0m; zsh[wv][col2 + 1] = z1m;
  __syncthreads();
  if (tid < 128) {
    float mz = zsh[0][tid];
#pragma unroll
    for (int w2 = 1; w2 < 16; ++w2) mz = fmaxf(mz, zsh[w2][tid]);
    wmax[(b * 4 + qt) * H_ + tid] = mz;
    __threadfence();
  }
  __syncthreads();
  if (tid == 0) lastf = (atomicAdd(&cnt[1], 1u) == 255u);
  __syncthreads();
  if (!lastf) return;

  // ===== fused tail: pooled = tanh(max_q wmax + b1); out = pooled@W2 + b2 =====
  __threadfence();
  for (int idx = tid; idx < B_ * H_; idx += 1024) {
    const int bb = idx >> 7, h = idx & 127;
    float mz = wmax[(bb * 4) * H_ + h];
#pragma unroll
    for (int q2 = 1; q2 < 4; ++q2) mz = fmaxf(mz, wmax[(bb * 4 + q2) * H_ + h]);
    ps[bb][h] = tanhf(mz + b1[h]);
  }
  __syncthreads();
  if (tid < B_ * C_) {
    const int bb = tid / C_, c = tid % C_;
    float s = b2[c];
#pragma unroll 8
    for (int k = 0; k < H_; ++k) s = fmaf(ps[bb][k], W2[k * C_ + c], s);
    out[tid] = s;
  }
}

extern "C" void kernel_launch(void* const* d_in, const int* in_sizes, int n_in,
                              void* d_out, int out_size, void* d_ws, size_t ws_size,
                              hipStream_t stream) {
  const int* x = (const int*)d_in[0];
  const float* emb = (const float*)d_in[1];
  const float* alpha = (const float*)d_in[2];
  const float* beta = (const float*)d_in[3];
  const float* W1 = (const float*)d_in[4];
  const float* b1 = (const float*)d_in[5];
  const float* W2 = (const float*)d_in[6];
  const float* b2 = (const float*)d_in[7];
  (void)in_sizes; (void)n_in; (void)out_size; (void)ws_size;

  char* ws = (char*)d_ws;
  unsigned* mm = (unsigned*)ws;
  unsigned* cnt = (unsigned*)(ws + 8);
  unsigned* bm = (unsigned*)(ws + 16);
  float* cArr = (float*)(ws + 8192);
  float* pArr = (float*)(ws + 16384);
  float* SArr = (float*)(ws + 24576);
  unsigned short* embW1 = (unsigned short*)(ws + 65536);
  float* psum = (float*)(ws + 12865536);
  float* wmax = (float*)(ws + 14962688);

  k_init<<<1, 512, 0, stream>>>(mm, cnt, bm);
  k_bitmap<<<(B_ * L_) / 256, 256, 0, stream>>>(x, bm);
  k_gemm<<<NGB, 512, 0, stream>>>(emb, W1, bm, mm, embW1, cnt,
                                  alpha, beta, cArr, pArr, SArr);
  k_psum<<<1024, 256, 0, stream>>>(x, embW1, pArr, psum);
  k_zmax<<<256, 1024, 0, stream>>>(x, embW1, cArr, pArr, SArr, psum, beta, mm,
                                   wmax, cnt, b1, W2, b2, (float*)d_out);
}

// Round 11
// 114.792 us; speedup vs baseline: 1.4498x; 1.1290x over previous
//
#include <hip/hip_runtime.h>
#include <hip/hip_bf16.h>
#include <math.h>

#define B_ 64
#define L_ 2048
#define V_ 50000
#define E_ 300
#define H_ 128
#define C_ 10
#define NGB 782            // 64-row tiles (2 subtiles of 32)

// ws layout (bytes):
//     0: mm[2] (encoded min/max)      8: cnt[2] (done counters)  [same 64B line]
//    16: bitmap[1563] (6252 B)
//  8192: cArr[2048] f32   16384: pArr[2048] f32   24576: SArr[128] f32
// 65536: embW1 bf16 [50000][128] (12.8 MB)
// 12865536: psum f32 [64][64][128] (2 MB)
// 14962688: wmax f32 [64][4][128] (128 KB)

typedef short bf16x8 __attribute__((ext_vector_type(8)));
typedef float f32x4 __attribute__((ext_vector_type(4)));

__device__ __forceinline__ unsigned enc_f32(float f) {
  unsigned u = __float_as_uint(f);
  return (u & 0x80000000u) ? ~u : (u | 0x80000000u);
}
__device__ __forceinline__ float dec_f32(unsigned u) {
  unsigned v = (u & 0x80000000u) ? (u ^ 0x80000000u) : ~u;
  return __uint_as_float(v);
}
__device__ __forceinline__ unsigned short f2bf(float f) {  // RNE f32->bf16
  unsigned u = __float_as_uint(f);
  unsigned r = 0x7FFFu + ((u >> 16) & 1u);
  return (unsigned short)((u + r) >> 16);
}

// ---- K0: init mm + counters + zero bitmap ----
__global__ __launch_bounds__(512) void k_init(unsigned* __restrict__ mm,
                                              unsigned* __restrict__ cnt,
                                              unsigned* __restrict__ bm) {
  const int t = threadIdx.x;
  if (t == 0) { mm[0] = 0xFFFFFFFFu; mm[1] = 0u; cnt[0] = 0u; cnt[1] = 0u; }
  for (int i = t; i < 1563; i += 512) bm[i] = 0u;
}

// ---- K1: presence bitmap ----
__global__ __launch_bounds__(256) void k_bitmap(const int* __restrict__ x,
                                                unsigned* __restrict__ bm) {
  const int i = blockIdx.x * 256 + threadIdx.x;
  const int v = x[i];
  atomicOr(&bm[v >> 5], 1u << (v & 31));
}

// ---- K2: embW1 = bf16(emb @ W1) + presence min/max. NO threadfence:
// mm-atomic ACKs are consumed (asm) before the cnt signal; mm & cnt share
// one L2 line, so ordering is guaranteed without draining embW1 stores.
// Last-finishing block runs the parallel Newton scan + SArr. ----
__global__ __launch_bounds__(512) void k_gemm(
    const float* __restrict__ emb, const float* __restrict__ W1,
    const unsigned* __restrict__ bm, unsigned* __restrict__ mm,
    unsigned short* __restrict__ embW1, unsigned* __restrict__ cnt,
    const float* __restrict__ alphaP, const float* __restrict__ betaP,
    float* __restrict__ cArr, float* __restrict__ pArr,
    float* __restrict__ SArr) {
  __shared__ unsigned short at[32][328];   // bf16 subtile, 20,992 B
  __shared__ float smn[8], smx[8];
  __shared__ bool lastf;
  const int r0 = blockIdx.x * 64;
  const int tid = threadIdx.x;
  const int w = tid >> 6;
  const int lane = tid & 63;
  const int arow = lane & 15;
  const int g = lane >> 4;
  const int rr = tid >> 4;          // staging: row 0..31, 16 thr/row
  const int c16 = tid & 15;

  float mn = 3.4e38f, mx = -3.4e38f;

  // ---- issue subtile-0 loads ----
  float4 pf[5];
  {
    const int row = r0 + rr;
    const float* rp = emb + (size_t)((row < V_) ? row : (V_ - 1)) * E_;
#pragma unroll
    for (int j = 0; j < 5; ++j) {
      const int k0 = c16 * 4 + 64 * j;
      pf[j] = (k0 < E_) ? *(const float4*)(rp + k0) : float4{0, 0, 0, 0};
    }
  }

  // ---- A-fragments: W1^T, m-dim = H col, k = 32kt + 8g + i ----
  bf16x8 bfr[10];
  const int col = w * 16 + arow;
#pragma unroll
  for (int kt = 0; kt < 10; ++kt) {
    const int k0 = kt * 32 + g * 8;
#pragma unroll
    for (int i = 0; i < 8; ++i) {
      const int k = k0 + i;
      bfr[kt][i] = (short)((k < E_) ? f2bf(W1[k * H_ + col]) : 0);
    }
  }

#pragma unroll
  for (int st = 0; st < 2; ++st) {
    const int row = r0 + st * 32 + rr;
    const bool pres = (row < V_) && ((bm[row >> 5] >> (row & 31)) & 1u);
#pragma unroll
    for (int j = 0; j < 5; ++j) {
      const int k0 = c16 * 4 + 64 * j;
      if (k0 < 320) {
        const float4 v = pf[j];
        if (pres && k0 < E_) {
          mn = fminf(mn, fminf(fminf(v.x, v.y), fminf(v.z, v.w)));
          mx = fmaxf(mx, fmaxf(fmaxf(v.x, v.y), fmaxf(v.z, v.w)));
        }
        unsigned long long p = 0ull;
        if (k0 < E_)
          p = (unsigned long long)f2bf(v.x) | ((unsigned long long)f2bf(v.y) << 16)
            | ((unsigned long long)f2bf(v.z) << 32) | ((unsigned long long)f2bf(v.w) << 48);
        *(unsigned long long*)&at[rr][k0] = p;
      }
    }
    if (st == 0) {                       // issue subtile-1 loads now
      const int row1 = r0 + 32 + rr;
      const float* rp = emb + (size_t)((row1 < V_) ? row1 : (V_ - 1)) * E_;
#pragma unroll
      for (int j = 0; j < 5; ++j) {
        const int k0 = c16 * 4 + 64 * j;
        pf[j] = (k0 < E_) ? *(const float4*)(rp + k0) : float4{0, 0, 0, 0};
      }
    }
    __syncthreads();                     // subtile st staged
#pragma unroll
    for (int rt = 0; rt < 2; ++rt) {
      f32x4 acc = {0, 0, 0, 0};
#pragma unroll
      for (int kt = 0; kt < 10; ++kt) {
        bf16x8 bb = *(const bf16x8*)&at[rt * 16 + arow][kt * 32 + g * 8];
        acc = __builtin_amdgcn_mfma_f32_16x16x32_bf16(bfr[kt], bb, acc, 0, 0, 0);
      }
      const int grow = r0 + st * 32 + rt * 16 + arow;
      if (grow < V_) {
        unsigned long long p = (unsigned long long)f2bf(acc[0])
                             | ((unsigned long long)f2bf(acc[1]) << 16)
                             | ((unsigned long long)f2bf(acc[2]) << 32)
                             | ((unsigned long long)f2bf(acc[3]) << 48);
        *(unsigned long long*)&embW1[(size_t)grow * H_ + w * 16 + g * 4] = p;
      }
    }
    __syncthreads();                     // reads done before re-staging LDS
  }

  // ---- block min/max -> atomics; dependency-ordered done-counter ----
#pragma unroll
  for (int s = 1; s < 64; s <<= 1) {
    mn = fminf(mn, __shfl_xor(mn, s));
    mx = fmaxf(mx, __shfl_xor(mx, s));
  }
  if (lane == 0) { smn[w] = mn; smx[w] = mx; }
  __syncthreads();
  if (tid == 0) {
#pragma unroll
    for (int i = 1; i < 8; ++i) { mn = fminf(mn, smn[i]); mx = fmaxf(mx, smx[i]); }
    unsigned o0 = atomicMin(&mm[0], enc_f32(mn));
    unsigned o1 = atomicMax(&mm[1], enc_f32(mx));
    asm volatile("" :: "v"(o0), "v"(o1));  // wait mm ACKs (L2) before signal
    lastf = (atomicAdd(&cnt[0], 1u) == NGB - 1u);
  }
  __syncthreads();
  if (!lastf) return;

  // ===== fused Newton scan for c_t, P_t (tid<64) + SArr (tid 64..191) =====
  if (tid < 64) {
    const int ln = tid;
    const float alpha = alphaP[0];
    const float lmn = dec_f32(atomicOr(&mm[0], 0u));
    const float lmx = dec_f32(atomicOr(&mm[1], 0u));
    const float sb = betaP[0] * lmn / (lmx - lmn);   // -beta*xn(xe=0)
    const float tl = (float)(ln * 32);

    float c = sqrtf(fmaf(2.0f * alpha, tl, 1.0f));
    if (fabsf(sb) > 1e-7f) {
      const float isb = 1.0f / sb;
      const float k2 = alpha * isb * isb;
      const float d0 = fmaxf(alpha + sb, 1e-8f);
#pragma unroll
      for (int it = 0; it < 4; ++it) {
        const float den = fmaxf(fmaf(sb, c, alpha), 1e-8f);
        const float T = (c - 1.0f) * isb - k2 * logf(den / d0);
        c = c - (T - tl) * den / c;
        c = fminf(fmaxf(c, 1.0f), 1e3f);
      }
    }
    if (ln == 0) c = 1.0f;

#pragma unroll
    for (int sw = 0; sw < 3; ++sw) {
      float cc = c, d = 1.0f;
#pragma unroll
      for (int j = 0; j < 32; ++j) {
        const float r = __builtin_amdgcn_rcpf(cc);
        d *= fmaf(-alpha * r, r, 1.0f);
        cc = fmaf(alpha, r, cc) + sb;
      }
      float A = d, Bv = fmaf(-d, c, cc);
#pragma unroll
      for (int o = 1; o < 64; o <<= 1) {
        const float A2 = __shfl_up(A, o);
        const float B2 = __shfl_up(Bv, o);
        if (ln >= o) { Bv = fmaf(A, B2, Bv); A *= A2; }
      }
      const float As = __shfl_up(A, 1);
      const float Bs = __shfl_up(Bv, 1);
      if (ln > 0) c = As + Bs;
    }

    float av[32];
    float cc = c, Q = 1.0f;
#pragma unroll
    for (int j = 0; j < 32; ++j) {
      cArr[ln * 32 + j] = cc;
      const float r = __builtin_amdgcn_rcpf(cc);
      const float a = fmaf(-alpha * r, r, 1.0f);
      av[j] = a; Q *= a;
      cc = fmaf(alpha, r, cc) + sb;
    }
    float Pp = Q;
#pragma unroll
    for (int o = 1; o < 64; o <<= 1) {
      const float q2 = __shfl_up(Pp, o);
      if (ln >= o) Pp *= q2;
    }
    const float Ps = __shfl_up(Pp, 1);
    float P = (ln == 0) ? 1.0f : Ps;
#pragma unroll
    for (int j = 0; j < 32; ++j) {
      pArr[ln * 32 + j] = P;
      P *= av[j];
    }
  } else if (tid < 192) {
    const int cl = tid - 64;
    float s = 0.0f;
    for (int k = 0; k < E_; ++k) s += W1[k * H_ + cl];
    SArr[cl] = s;
  }
}

// ---- K3: per-(b, 32-step segment) partial sums. tok/q preloaded into
// lanes 0-31, per-step via __shfl -> all 32 row-gathers independent. ----
__global__ __launch_bounds__(256) void k_psum(const int* __restrict__ x,
                                              const unsigned short* __restrict__ embW1,
                                              const float* __restrict__ pArr,
                                              float* __restrict__ psum) {
  const int bid = blockIdx.x;             // 1024 blocks
  const int b = bid >> 4, sq = bid & 15;
  const int wv = threadIdx.x >> 6, lane = threadIdx.x & 63;
  const int v = sq * 4 + wv;              // 0..63
  const int t0 = v * 32;
  const int col2 = lane * 2;
  int tokv = 0; float qv = 0.0f;
  if (lane < 32) {
    const int t = t0 + lane;
    tokv = x[b * L_ + t];
    qv = (t + 1 < L_) ? __builtin_amdgcn_rcpf(pArr[t + 1]) : 0.0f;
  }
  float s0 = 0.f, s1 = 0.f;
#pragma unroll
  for (int j = 0; j < 32; ++j) {
    const int tok = __shfl(tokv, j);
    const float q = __shfl(qv, j);
    const unsigned y2 = *(const unsigned*)(embW1 + (size_t)tok * H_ + col2);
    s0 = fmaf(q, __uint_as_float(y2 << 16), s0);
    s1 = fmaf(q, __uint_as_float(y2 & 0xFFFF0000u), s1);
  }
  float* p = psum + (size_t)(b * 64 + v) * H_ + col2;
  p[0] = s0; p[1] = s1;
}

// ---- K4: z-max per (b, quarter). psum cached in LDS; wmax written via
// atomicExch (ACK-consumed) -> no threadfence; last block fuses tanh+W2. ----
__global__ __launch_bounds__(1024) void k_zmax(
    const int* __restrict__ x, const unsigned short* __restrict__ embW1,
    const float* __restrict__ cArr, const float* __restrict__ pArr,
    const float* __restrict__ SArr, const float* __restrict__ psum,
    const float* __restrict__ betaP, const unsigned* __restrict__ mm,
    float* __restrict__ wmax, unsigned* __restrict__ cnt,
    const float* __restrict__ b1, const float* __restrict__ W2,
    const float* __restrict__ b2, float* __restrict__ out) {
  __shared__ float ps[64][128];           // psum cache; reused as pooled staging
  __shared__ float zsh[16][128];
  __shared__ bool lastf;
  const int bid = blockIdx.x;             // 256 blocks
  const int b = bid >> 2, qt = bid & 3;
  const int tid = threadIdx.x;
  const int wv = tid >> 6, lane = tid & 63;
  const int v = qt * 16 + wv;             // 0..63
  const int t0 = v * 32;
  const int col2 = lane * 2;

  for (int i = tid; i < 64 * 128; i += 1024)      // cache psum[b][*][*]
    ps[i >> 7][i & 127] = psum[(size_t)(b * 64) * H_ + i];

  int tokv = 0; float qv = 0.f, cv = 0.f, pv = 0.f;
  if (lane < 32) {
    const int t = t0 + lane;
    tokv = x[b * L_ + t];
    cv = cArr[t];
    pv = pArr[t];
    qv = (t + 1 < L_) ? __builtin_amdgcn_rcpf(pArr[t + 1]) : 0.0f;
  }
  const float mn = dec_f32(mm[0]), mx = dec_f32(mm[1]);
  const float binv = betaP[0] / (mx - mn);
  const float S0 = SArr[col2], S1 = SArr[col2 + 1];
  __syncthreads();

  float m0 = 0.f, m1 = 0.f;               // prefix m at t0 from LDS
  for (int u = 0; u < v; ++u) { m0 += ps[u][col2]; m1 += ps[u][col2 + 1]; }

  float z0m = -3.4e38f, z1m = -3.4e38f;
#pragma unroll
  for (int j = 0; j < 32; ++j) {
    const int tok = __shfl(tokv, j);
    const float ct = __shfl(cv, j);
    const float gt = binv * __shfl(pv, j);
    const float q = __shfl(qv, j);
    const unsigned y2 = *(const unsigned*)(embW1 + (size_t)tok * H_ + col2);
    z0m = fmaxf(z0m, fmaf(-gt, m0, ct * S0));   // z uses m BEFORE adding term t
    z1m = fmaxf(z1m, fmaf(-gt, m1, ct * S1));
    m0 = fmaf(q, __uint_as_float(y2 << 16), m0);
    m1 = fmaf(q, __uint_as_float(y2 & 0xFFFF0000u), m1);
  }
  zsh[wv][col2] = z0m; zsh[wv][col2 + 1] = z1m;
  __syncthreads();
  if (tid < 128) {
    float mz = zsh[0][tid];
#pragma unroll
    for (int w2 = 1; w2 < 16; ++w2) mz = fmaxf(mz, zsh[w2][tid]);
    unsigned old = atomicExch((unsigned*)&wmax[(b * 4 + qt) * H_ + tid],
                              __float_as_uint(mz));
    asm volatile("" :: "v"(old));         // wait L2 ACK -> visible before signal
  }
  __syncthreads();
  if (tid == 0) lastf = (atomicAdd(&cnt[1], 1u) == 255u);
  __syncthreads();
  if (!lastf) return;

  // ===== fused tail: pooled = tanh(max_q wmax + b1); out = pooled@W2 + b2 =====
  for (int idx = tid; idx < B_ * H_; idx += 1024) {
    const int bb = idx >> 7, h = idx & 127;
    float mz = wmax[(bb * 4) * H_ + h];
#pragma unroll
    for (int q2 = 1; q2 < 4; ++q2) mz = fmaxf(mz, wmax[(bb * 4 + q2) * H_ + h]);
    ps[bb][h] = tanhf(mz + b1[h]);
  }
  __syncthreads();
  if (tid < B_ * C_) {
    const int bb = tid / C_, c = tid % C_;
    float s = b2[c];
#pragma unroll 8
    for (int k = 0; k < H_; ++k) s = fmaf(ps[bb][k], W2[k * C_ + c], s);
    out[tid] = s;
  }
}

extern "C" void kernel_launch(void* const* d_in, const int* in_sizes, int n_in,
                              void* d_out, int out_size, void* d_ws, size_t ws_size,
                              hipStream_t stream) {
  const int* x = (const int*)d_in[0];
  const float* emb = (const float*)d_in[1];
  const float* alpha = (const float*)d_in[2];
  const float* beta = (const float*)d_in[3];
  const float* W1 = (const float*)d_in[4];
  const float* b1 = (const float*)d_in[5];
  const float* W2 = (const float*)d_in[6];
  const float* b2 = (const float*)d_in[7];
  (void)in_sizes; (void)n_in; (void)out_size; (void)ws_size;

  char* ws = (char*)d_ws;
  unsigned* mm = (unsigned*)ws;
  unsigned* cnt = (unsigned*)(ws + 8);
  unsigned* bm = (unsigned*)(ws + 16);
  float* cArr = (float*)(ws + 8192);
  float* pArr = (float*)(ws + 16384);
  float* SArr = (float*)(ws + 24576);
  unsigned short* embW1 = (unsigned short*)(ws + 65536);
  float* psum = (float*)(ws + 12865536);
  float* wmax = (float*)(ws + 14962688);

  k_init<<<1, 512, 0, stream>>>(mm, cnt, bm);
  k_bitmap<<<(B_ * L_) / 256, 256, 0, stream>>>(x, bm);
  k_gemm<<<NGB, 512, 0, stream>>>(emb, W1, bm, mm, embW1, cnt,
                                  alpha, beta, cArr, pArr, SArr);
  k_psum<<<1024, 256, 0, stream>>>(x, embW1, pArr, psum);
  k_zmax<<<256, 1024, 0, stream>>>(x, embW1, cArr, pArr, SArr, psum, beta, mm,
                                   wmax, cnt, b1, W2, b2, (float*)d_out);
}

// Round 12
// 101.576 us; speedup vs baseline: 1.6384x; 1.1301x over previous
//
#include <hip/hip_runtime.h>
#include <hip/hip_bf16.h>
#include <math.h>

#define B_ 64
#define L_ 2048
#define V_ 50000
#define E_ 300
#define H_ 128
#define C_ 10
#define NGB 782            // 64-row tiles (2 subtiles of 32)

// ws layout (bytes):
//     0: cnt[2] (done counters)
//    16: bitmap[1563] (6252 B)
//  8192: cArr[2048] f32   16384: pArr[2048] f32   24576: SArr[128] f32
// 25600: mmf[1] f32 (binv, published by scan block)
// 32768: bmn[782] u32 (per-block min slots)   36864: bmx[782] u32
// 65536: embW1 bf16 [50000][128] (12.8 MB)
// 12865536: psum f32 [64][64][128] (2 MB)
// 14962688: wmax f32 [64][4][128] (128 KB)

typedef short bf16x8 __attribute__((ext_vector_type(8)));
typedef float f32x4 __attribute__((ext_vector_type(4)));

__device__ __forceinline__ unsigned enc_f32(float f) {
  unsigned u = __float_as_uint(f);
  return (u & 0x80000000u) ? ~u : (u | 0x80000000u);
}
__device__ __forceinline__ float dec_f32(unsigned u) {
  unsigned v = (u & 0x80000000u) ? (u ^ 0x80000000u) : ~u;
  return __uint_as_float(v);
}
__device__ __forceinline__ unsigned short f2bf(float f) {  // RNE f32->bf16
  unsigned u = __float_as_uint(f);
  unsigned r = 0x7FFFu + ((u >> 16) & 1u);
  return (unsigned short)((u + r) >> 16);
}

// ---- K0: init counters + zero bitmap ----
__global__ __launch_bounds__(512) void k_init(unsigned* __restrict__ cnt,
                                              unsigned* __restrict__ bm) {
  const int t = threadIdx.x;
  if (t == 0) { cnt[0] = 0u; cnt[1] = 0u; }
  for (int i = t; i < 1563; i += 512) bm[i] = 0u;
}

// ---- K1: presence bitmap ----
__global__ __launch_bounds__(256) void k_bitmap(const int* __restrict__ x,
                                                unsigned* __restrict__ bm) {
  const int i = blockIdx.x * 256 + threadIdx.x;
  const int v = x[i];
  atomicOr(&bm[v >> 5], 1u << (v & 31));
}

// ---- K2: embW1 = bf16(emb @ W1) + presence min/max. Decontended signal:
// per-block min/max -> own slot (2 independent atomicExch, 1 combined ACK
// wait), then one pipelined atomicAdd on cnt. Last block reduces the slots
// and runs the Newton scan + SArr + publishes binv. ----
__global__ __launch_bounds__(512) void k_gemm(
    const float* __restrict__ emb, const float* __restrict__ W1,
    const unsigned* __restrict__ bm, unsigned* __restrict__ bmn,
    unsigned* __restrict__ bmx, unsigned short* __restrict__ embW1,
    unsigned* __restrict__ cnt,
    const float* __restrict__ alphaP, const float* __restrict__ betaP,
    float* __restrict__ cArr, float* __restrict__ pArr,
    float* __restrict__ SArr, float* __restrict__ mmf) {
  __shared__ unsigned short at[32][328];   // bf16 subtile, 20,992 B
  __shared__ float smn[8], smx[8];
  __shared__ unsigned umn[8], umx[8];
  __shared__ bool lastf;
  const int r0 = blockIdx.x * 64;
  const int tid = threadIdx.x;
  const int w = tid >> 6;
  const int lane = tid & 63;
  const int arow = lane & 15;
  const int g = lane >> 4;
  const int rr = tid >> 4;          // staging: row 0..31, 16 thr/row
  const int c16 = tid & 15;

  float mn = 3.4e38f, mx = -3.4e38f;

  // ---- issue subtile-0 loads ----
  float4 pf[5];
  {
    const int row = r0 + rr;
    const float* rp = emb + (size_t)((row < V_) ? row : (V_ - 1)) * E_;
#pragma unroll
    for (int j = 0; j < 5; ++j) {
      const int k0 = c16 * 4 + 64 * j;
      pf[j] = (k0 < E_) ? *(const float4*)(rp + k0) : float4{0, 0, 0, 0};
    }
  }

  // ---- A-fragments: W1^T, m-dim = H col, k = 32kt + 8g + i ----
  bf16x8 bfr[10];
  const int col = w * 16 + arow;
#pragma unroll
  for (int kt = 0; kt < 10; ++kt) {
    const int k0 = kt * 32 + g * 8;
#pragma unroll
    for (int i = 0; i < 8; ++i) {
      const int k = k0 + i;
      bfr[kt][i] = (short)((k < E_) ? f2bf(W1[k * H_ + col]) : 0);
    }
  }

#pragma unroll
  for (int st = 0; st < 2; ++st) {
    const int row = r0 + st * 32 + rr;
    const bool pres = (row < V_) && ((bm[row >> 5] >> (row & 31)) & 1u);
#pragma unroll
    for (int j = 0; j < 5; ++j) {
      const int k0 = c16 * 4 + 64 * j;
      if (k0 < 320) {
        const float4 v = pf[j];
        if (pres && k0 < E_) {
          mn = fminf(mn, fminf(fminf(v.x, v.y), fminf(v.z, v.w)));
          mx = fmaxf(mx, fmaxf(fmaxf(v.x, v.y), fmaxf(v.z, v.w)));
        }
        unsigned long long p = 0ull;
        if (k0 < E_)
          p = (unsigned long long)f2bf(v.x) | ((unsigned long long)f2bf(v.y) << 16)
            | ((unsigned long long)f2bf(v.z) << 32) | ((unsigned long long)f2bf(v.w) << 48);
        *(unsigned long long*)&at[rr][k0] = p;
      }
    }
    if (st == 0) {                       // issue subtile-1 loads now
      const int row1 = r0 + 32 + rr;
      const float* rp = emb + (size_t)((row1 < V_) ? row1 : (V_ - 1)) * E_;
#pragma unroll
      for (int j = 0; j < 5; ++j) {
        const int k0 = c16 * 4 + 64 * j;
        pf[j] = (k0 < E_) ? *(const float4*)(rp + k0) : float4{0, 0, 0, 0};
      }
    }
    __syncthreads();                     // subtile st staged
#pragma unroll
    for (int rt = 0; rt < 2; ++rt) {
      f32x4 acc = {0, 0, 0, 0};
#pragma unroll
      for (int kt = 0; kt < 10; ++kt) {
        bf16x8 bb = *(const bf16x8*)&at[rt * 16 + arow][kt * 32 + g * 8];
        acc = __builtin_amdgcn_mfma_f32_16x16x32_bf16(bfr[kt], bb, acc, 0, 0, 0);
      }
      const int grow = r0 + st * 32 + rt * 16 + arow;
      if (grow < V_) {
        unsigned long long p = (unsigned long long)f2bf(acc[0])
                             | ((unsigned long long)f2bf(acc[1]) << 16)
                             | ((unsigned long long)f2bf(acc[2]) << 32)
                             | ((unsigned long long)f2bf(acc[3]) << 48);
        *(unsigned long long*)&embW1[(size_t)grow * H_ + w * 16 + g * 4] = p;
      }
    }
    __syncthreads();                     // reads done before re-staging LDS
  }

  // ---- block min/max -> own slot; single counted atomic ----
#pragma unroll
  for (int s = 1; s < 64; s <<= 1) {
    mn = fminf(mn, __shfl_xor(mn, s));
    mx = fmaxf(mx, __shfl_xor(mx, s));
  }
  if (lane == 0) { smn[w] = mn; smx[w] = mx; }
  __syncthreads();
  if (tid == 0) {
#pragma unroll
    for (int i = 1; i < 8; ++i) { mn = fminf(mn, smn[i]); mx = fmaxf(mx, smx[i]); }
    unsigned o0 = atomicExch(&bmn[blockIdx.x], enc_f32(mn));
    unsigned o1 = atomicExch(&bmx[blockIdx.x], enc_f32(mx));
    asm volatile("" :: "v"(o0), "v"(o1));  // both ACKs, one round trip
    lastf = (atomicAdd(&cnt[0], 1u) == NGB - 1u);
  }
  __syncthreads();
  if (!lastf) return;

  // ===== last block: global min/max reduce over slots =====
  unsigned vmn = 0xFFFFFFFFu, vmx = 0u;
  for (int i = tid; i < NGB; i += 512) {
    const unsigned a = atomicOr(&bmn[i], 0u);   // coherent device-scope read
    const unsigned b = atomicOr(&bmx[i], 0u);
    vmn = (a < vmn) ? a : vmn;
    vmx = (b > vmx) ? b : vmx;
  }
#pragma unroll
  for (int s = 1; s < 64; s <<= 1) {
    const unsigned a = (unsigned)__shfl_xor((int)vmn, s);
    const unsigned b = (unsigned)__shfl_xor((int)vmx, s);
    vmn = (a < vmn) ? a : vmn;
    vmx = (b > vmx) ? b : vmx;
  }
  if (lane == 0) { umn[w] = vmn; umx[w] = vmx; }
  __syncthreads();
  unsigned fmn = umn[0], fmx = umx[0];
#pragma unroll
  for (int i = 1; i < 8; ++i) {
    fmn = (umn[i] < fmn) ? umn[i] : fmn;
    fmx = (umx[i] > fmx) ? umx[i] : fmx;
  }
  const float lmn = dec_f32(fmn), lmx = dec_f32(fmx);
  if (tid == 255) mmf[0] = betaP[0] / (lmx - lmn);   // binv for k_zmax

  // ===== fused Newton scan for c_t, P_t (tid<64) + SArr (tid 64..191) =====
  if (tid < 64) {
    const int ln = tid;
    const float alpha = alphaP[0];
    const float sb = betaP[0] * lmn / (lmx - lmn);   // -beta*xn(xe=0)
    const float tl = (float)(ln * 32);

    float c = sqrtf(fmaf(2.0f * alpha, tl, 1.0f));
    if (fabsf(sb) > 1e-7f) {
      const float isb = 1.0f / sb;
      const float k2 = alpha * isb * isb;
      const float d0 = fmaxf(alpha + sb, 1e-8f);
#pragma unroll
      for (int it = 0; it < 4; ++it) {
        const float den = fmaxf(fmaf(sb, c, alpha), 1e-8f);
        const float T = (c - 1.0f) * isb - k2 * logf(den / d0);
        c = c - (T - tl) * den / c;
        c = fminf(fmaxf(c, 1.0f), 1e3f);
      }
    }
    if (ln == 0) c = 1.0f;

#pragma unroll
    for (int sw = 0; sw < 3; ++sw) {
      float cc = c, d = 1.0f;
#pragma unroll
      for (int j = 0; j < 32; ++j) {
        const float r = __builtin_amdgcn_rcpf(cc);
        d *= fmaf(-alpha * r, r, 1.0f);
        cc = fmaf(alpha, r, cc) + sb;
      }
      float A = d, Bv = fmaf(-d, c, cc);
#pragma unroll
      for (int o = 1; o < 64; o <<= 1) {
        const float A2 = __shfl_up(A, o);
        const float B2 = __shfl_up(Bv, o);
        if (ln >= o) { Bv = fmaf(A, B2, Bv); A *= A2; }
      }
      const float As = __shfl_up(A, 1);
      const float Bs = __shfl_up(Bv, 1);
      if (ln > 0) c = As + Bs;
    }

    float av[32];
    float cc = c, Q = 1.0f;
#pragma unroll
    for (int j = 0; j < 32; ++j) {
      cArr[ln * 32 + j] = cc;
      const float r = __builtin_amdgcn_rcpf(cc);
      const float a = fmaf(-alpha * r, r, 1.0f);
      av[j] = a; Q *= a;
      cc = fmaf(alpha, r, cc) + sb;
    }
    float Pp = Q;
#pragma unroll
    for (int o = 1; o < 64; o <<= 1) {
      const float q2 = __shfl_up(Pp, o);
      if (ln >= o) Pp *= q2;
    }
    const float Ps = __shfl_up(Pp, 1);
    float P = (ln == 0) ? 1.0f : Ps;
#pragma unroll
    for (int j = 0; j < 32; ++j) {
      pArr[ln * 32 + j] = P;
      P *= av[j];
    }
  } else if (tid < 192) {
    const int cl = tid - 64;
    float s = 0.0f;
    for (int k = 0; k < E_; ++k) s += W1[k * H_ + cl];
    SArr[cl] = s;
  }
}

// ---- K3: per-(b, 32-step segment) partial sums. tok/q preloaded into
// lanes 0-31, per-step via __shfl -> all 32 row-gathers independent. ----
__global__ __launch_bounds__(256) void k_psum(const int* __restrict__ x,
                                              const unsigned short* __restrict__ embW1,
                                              const float* __restrict__ pArr,
                                              float* __restrict__ psum) {
  const int bid = blockIdx.x;             // 1024 blocks
  const int b = bid >> 4, sq = bid & 15;
  const int wv = threadIdx.x >> 6, lane = threadIdx.x & 63;
  const int v = sq * 4 + wv;              // 0..63
  const int t0 = v * 32;
  const int col2 = lane * 2;
  int tokv = 0; float qv = 0.0f;
  if (lane < 32) {
    const int t = t0 + lane;
    tokv = x[b * L_ + t];
    qv = (t + 1 < L_) ? __builtin_amdgcn_rcpf(pArr[t + 1]) : 0.0f;
  }
  float s0 = 0.f, s1 = 0.f;
#pragma unroll
  for (int j = 0; j < 32; ++j) {
    const int tok = __shfl(tokv, j);
    const float q = __shfl(qv, j);
    const unsigned y2 = *(const unsigned*)(embW1 + (size_t)tok * H_ + col2);
    s0 = fmaf(q, __uint_as_float(y2 << 16), s0);
    s1 = fmaf(q, __uint_as_float(y2 & 0xFFFF0000u), s1);
  }
  float* p = psum + (size_t)(b * 64 + v) * H_ + col2;
  p[0] = s0; p[1] = s1;
}

// ---- K4: z-max per (b, quarter). psum cached in LDS; wmax written via
// atomicExch (ACK-consumed); last block fuses tanh + W2 matvec. ----
__global__ __launch_bounds__(1024) void k_zmax(
    const int* __restrict__ x, const unsigned short* __restrict__ embW1,
    const float* __restrict__ cArr, const float* __restrict__ pArr,
    const float* __restrict__ SArr, const float* __restrict__ psum,
    const float* __restrict__ mmf,
    float* __restrict__ wmax, unsigned* __restrict__ cnt,
    const float* __restrict__ b1, const float* __restrict__ W2,
    const float* __restrict__ b2, float* __restrict__ out) {
  __shared__ float ps[64][128];           // psum cache; reused as pooled staging
  __shared__ float zsh[16][128];
  __shared__ bool lastf;
  const int bid = blockIdx.x;             // 256 blocks
  const int b = bid >> 2, qt = bid & 3;
  const int tid = threadIdx.x;
  const int wv = tid >> 6, lane = tid & 63;
  const int v = qt * 16 + wv;             // 0..63
  const int t0 = v * 32;
  const int col2 = lane * 2;

  for (int i = tid; i < 64 * 128; i += 1024)      // cache psum[b][*][*]
    ps[i >> 7][i & 127] = psum[(size_t)(b * 64) * H_ + i];

  int tokv = 0; float qv = 0.f, cv = 0.f, pv = 0.f;
  if (lane < 32) {
    const int t = t0 + lane;
    tokv = x[b * L_ + t];
    cv = cArr[t];
    pv = pArr[t];
    qv = (t + 1 < L_) ? __builtin_amdgcn_rcpf(pArr[t + 1]) : 0.0f;
  }
  const float binv = mmf[0];
  const float S0 = SArr[col2], S1 = SArr[col2 + 1];
  __syncthreads();

  float m0 = 0.f, m1 = 0.f;               // prefix m at t0 from LDS
  for (int u = 0; u < v; ++u) { m0 += ps[u][col2]; m1 += ps[u][col2 + 1]; }

  float z0m = -3.4e38f, z1m = -3.4e38f;
#pragma unroll
  for (int j = 0; j < 32; ++j) {
    const int tok = __shfl(tokv, j);
    const float ct = __shfl(cv, j);
    const float gt = binv * __shfl(pv, j);
    const float q = __shfl(qv, j);
    const unsigned y2 = *(const unsigned*)(embW1 + (size_t)tok * H_ + col2);
    z0m = fmaxf(z0m, fmaf(-gt, m0, ct * S0));   // z uses m BEFORE adding term t
    z1m = fmaxf(z1m, fmaf(-gt, m1, ct * S1));
    m0 = fmaf(q, __uint_as_float(y2 << 16), m0);
    m1 = fmaf(q, __uint_as_float(y2 & 0xFFFF0000u), m1);
  }
  zsh[wv][col2] = z0m; zsh[wv][col2 + 1] = z1m;
  __syncthreads();
  if (tid < 128) {
    float mz = zsh[0][tid];
#pragma unroll
    for (int w2 = 1; w2 < 16; ++w2) mz = fmaxf(mz, zsh[w2][tid]);
    unsigned old = atomicExch((unsigned*)&wmax[(b * 4 + qt) * H_ + tid],
                              __float_as_uint(mz));
    asm volatile("" :: "v"(old));         // wait L2 ACK -> visible before signal
  }
  __syncthreads();
  if (tid == 0) lastf = (atomicAdd(&cnt[1], 1u) == 255u);
  __syncthreads();
  if (!lastf) return;

  // ===== fused tail: pooled = tanh(max_q wmax + b1); out = pooled@W2 + b2 =====
  for (int idx = tid; idx < B_ * H_; idx += 1024) {
    const int bb = idx >> 7, h = idx & 127;
    float mz = wmax[(bb * 4) * H_ + h];
#pragma unroll
    for (int q2 = 1; q2 < 4; ++q2) mz = fmaxf(mz, wmax[(bb * 4 + q2) * H_ + h]);
    ps[bb][h] = tanhf(mz + b1[h]);
  }
  __syncthreads();
  if (tid < B_ * C_) {
    const int bb = tid / C_, c = tid % C_;
    float s = b2[c];
#pragma unroll 8
    for (int k = 0; k < H_; ++k) s = fmaf(ps[bb][k], W2[k * C_ + c], s);
    out[tid] = s;
  }
}

extern "C" void kernel_launch(void* const* d_in, const int* in_sizes, int n_in,
                              void* d_out, int out_size, void* d_ws, size_t ws_size,
                              hipStream_t stream) {
  const int* x = (const int*)d_in[0];
  const float* emb = (const float*)d_in[1];
  const float* alpha = (const float*)d_in[2];
  const float* beta = (const float*)d_in[3];
  const float* W1 = (const float*)d_in[4];
  const float* b1 = (const float*)d_in[5];
  const float* W2 = (const float*)d_in[6];
  const float* b2 = (const float*)d_in[7];
  (void)in_sizes; (void)n_in; (void)out_size; (void)ws_size;

  char* ws = (char*)d_ws;
  unsigned* cnt = (unsigned*)ws;
  unsigned* bm = (unsigned*)(ws + 16);
  float* cArr = (float*)(ws + 8192);
  float* pArr = (float*)(ws + 16384);
  float* SArr = (float*)(ws + 24576);
  float* mmf = (float*)(ws + 25600);
  unsigned* bmn = (unsigned*)(ws + 32768);
  unsigned* bmx = (unsigned*)(ws + 36864);
  unsigned short* embW1 = (unsigned short*)(ws + 65536);
  float* psum = (float*)(ws + 12865536);
  float* wmax = (float*)(ws + 14962688);

  k_init<<<1, 512, 0, stream>>>(cnt, bm);
  k_bitmap<<<(B_ * L_) / 256, 256, 0, stream>>>(x, bm);
  k_gemm<<<NGB, 512, 0, stream>>>(emb, W1, bm, bmn, bmx, embW1, cnt,
                                  alpha, beta, cArr, pArr, SArr, mmf);
  k_psum<<<1024, 256, 0, stream>>>(x, embW1, pArr, psum);
  k_zmax<<<256, 1024, 0, stream>>>(x, embW1, cArr, pArr, SArr, psum, mmf,
                                   wmax, cnt, b1, W2, b2, (float*)d_out);
}

// Round 13
// 93.490 us; speedup vs baseline: 1.7801x; 1.0865x over previous
//
#include <hip/hip_runtime.h>
#include <hip/hip_bf16.h>
#include <math.h>

#define B_ 64
#define L_ 2048
#define V_ 50000
#define E_ 300
#define H_ 128
#define C_ 10
#define NGB 782            // 64-row tiles (2 subtiles of 32)

// ws layout (bytes):
//     0: cnt[2] (done counters)
//    16: bitmap[1563] (6252 B)
//  8192: cArr[2048] f32   16384: pArr[2048] f32   24576: SArr[128] f32
// 25600: mmf[1] f32 (binv)
// 32768: bmn[782] u32   36864: bmx[782] u32
// 65536: embW1 bf16 [50000][128] (12.8 MB)
// 12865536: w1t bf16 [128][320] (81920 B)  -- ALIASES psum: psum is written
//           only after k_gemm has finished reading w1t; k_bitmap rebuilds
//           w1t every replay before k_gemm. Deterministic per replay.
// 12865536: psum f32 [64][64][128] (2 MB)
// 14962688: wmax f32 [64][4][128] (128 KB)

typedef short bf16x8 __attribute__((ext_vector_type(8)));
typedef float f32x4 __attribute__((ext_vector_type(4)));

__device__ __forceinline__ unsigned enc_f32(float f) {
  unsigned u = __float_as_uint(f);
  return (u & 0x80000000u) ? ~u : (u | 0x80000000u);
}
__device__ __forceinline__ float dec_f32(unsigned u) {
  unsigned v = (u & 0x80000000u) ? (u ^ 0x80000000u) : ~u;
  return __uint_as_float(v);
}
__device__ __forceinline__ unsigned short f2bf(float f) {  // RNE f32->bf16
  unsigned u = __float_as_uint(f);
  unsigned r = 0x7FFFu + ((u >> 16) & 1u);
  return (unsigned short)((u + r) >> 16);
}
__device__ __forceinline__ unsigned cvtpk(float lo, float hi) {
  unsigned r;                     // D[15:0]=bf16(S0), D[31:16]=bf16(S1)
  asm("v_cvt_pk_bf16_f32 %0, %1, %2" : "=v"(r) : "v"(lo), "v"(hi));
  return r;
}

// ---- K0: init counters + zero bitmap ----
__global__ __launch_bounds__(512) void k_init(unsigned* __restrict__ cnt,
                                              unsigned* __restrict__ bm) {
  const int t = threadIdx.x;
  if (t == 0) { cnt[0] = 0u; cnt[1] = 0u; }
  for (int i = t; i < 1563; i += 512) bm[i] = 0u;
}

// ---- K1: presence bitmap + build w1t (bf16 W1^T fragment buffer) ----
__global__ __launch_bounds__(256) void k_bitmap(const int* __restrict__ x,
                                                unsigned* __restrict__ bm,
                                                const float* __restrict__ W1,
                                                unsigned short* __restrict__ w1t) {
  const int i = blockIdx.x * 256 + threadIdx.x;
  const int v = x[i];
  atomicOr(&bm[v >> 5], 1u << (v & 31));
  const int t = threadIdx.x;
  if (t < 80) {                            // 512 blocks x 80 = 40960 elems
    const int idx = blockIdx.x * 80 + t;
    const int col = idx / 320, k = idx % 320;
    w1t[idx] = (k < E_) ? f2bf(W1[k * H_ + col]) : 0;
  }
}

// ---- K2: embW1 = bf16(emb @ W1) + presence min/max. Fragments from w1t
// (10 x 16B vector loads); staging/epilogue via v_cvt_pk_bf16_f32.
// Per-block min/max -> own slot; pipelined done-counter; last block
// reduces slots, runs the Newton scan + SArr, publishes binv. ----
__global__ __launch_bounds__(512) void k_gemm(
    const float* __restrict__ emb, const float* __restrict__ W1,
    const unsigned* __restrict__ bm, unsigned* __restrict__ bmn,
    unsigned* __restrict__ bmx, unsigned short* __restrict__ embW1,
    unsigned* __restrict__ cnt, const unsigned short* __restrict__ w1t,
    const float* __restrict__ alphaP, const float* __restrict__ betaP,
    float* __restrict__ cArr, float* __restrict__ pArr,
    float* __restrict__ SArr, float* __restrict__ mmf) {
  __shared__ unsigned short at[32][328];   // bf16 subtile, 20,992 B
  __shared__ float smn[8], smx[8];
  __shared__ unsigned umn[8], umx[8];
  __shared__ bool lastf;
  const int r0 = blockIdx.x * 64;
  const int tid = threadIdx.x;
  const int w = tid >> 6;
  const int lane = tid & 63;
  const int arow = lane & 15;
  const int g = lane >> 4;
  const int rr = tid >> 4;          // staging: row 0..31, 16 thr/row
  const int c16 = tid & 15;

  float mn = 3.4e38f, mx = -3.4e38f;

  // ---- issue subtile-0 loads ----
  float4 pf[5];
  {
    const int row = r0 + rr;
    const float* rp = emb + (size_t)((row < V_) ? row : (V_ - 1)) * E_;
#pragma unroll
    for (int j = 0; j < 5; ++j) {
      const int k0 = c16 * 4 + 64 * j;
      pf[j] = (k0 < E_) ? *(const float4*)(rp + k0) : float4{0, 0, 0, 0};
    }
  }

  // ---- A-fragments: one 16-B vector load per kt from w1t ----
  bf16x8 bfr[10];
  const int col = w * 16 + arow;
  {
    const unsigned short* wp = w1t + col * 320 + g * 8;
#pragma unroll
    for (int kt = 0; kt < 10; ++kt)
      bfr[kt] = *(const bf16x8*)(wp + kt * 32);
  }

#pragma unroll
  for (int st = 0; st < 2; ++st) {
    const int row = r0 + st * 32 + rr;
    const bool pres = (row < V_) && ((bm[row >> 5] >> (row & 31)) & 1u);
#pragma unroll
    for (int j = 0; j < 5; ++j) {
      const int k0 = c16 * 4 + 64 * j;
      if (k0 < 320) {
        const float4 v = pf[j];
        if (pres && k0 < E_) {
          mn = fminf(mn, fminf(fminf(v.x, v.y), fminf(v.z, v.w)));
          mx = fmaxf(mx, fmaxf(fmaxf(v.x, v.y), fmaxf(v.z, v.w)));
        }
        uint2 p = {0u, 0u};
        if (k0 < E_) { p.x = cvtpk(v.x, v.y); p.y = cvtpk(v.z, v.w); }
        *(uint2*)&at[rr][k0] = p;
      }
    }
    if (st == 0) {                       // issue subtile-1 loads now
      const int row1 = r0 + 32 + rr;
      const float* rp = emb + (size_t)((row1 < V_) ? row1 : (V_ - 1)) * E_;
#pragma unroll
      for (int j = 0; j < 5; ++j) {
        const int k0 = c16 * 4 + 64 * j;
        pf[j] = (k0 < E_) ? *(const float4*)(rp + k0) : float4{0, 0, 0, 0};
      }
    }
    __syncthreads();                     // subtile st staged
#pragma unroll
    for (int rt = 0; rt < 2; ++rt) {
      f32x4 acc = {0, 0, 0, 0};
#pragma unroll
      for (int kt = 0; kt < 10; ++kt) {
        bf16x8 bb = *(const bf16x8*)&at[rt * 16 + arow][kt * 32 + g * 8];
        acc = __builtin_amdgcn_mfma_f32_16x16x32_bf16(bfr[kt], bb, acc, 0, 0, 0);
      }
      const int grow = r0 + st * 32 + rt * 16 + arow;
      if (grow < V_) {
        uint2 p = {cvtpk(acc[0], acc[1]), cvtpk(acc[2], acc[3])};
        *(uint2*)&embW1[(size_t)grow * H_ + w * 16 + g * 4] = p;
      }
    }
    __syncthreads();                     // reads done before re-staging LDS
  }

  // ---- block min/max -> own slot; single counted atomic ----
#pragma unroll
  for (int s = 1; s < 64; s <<= 1) {
    mn = fminf(mn, __shfl_xor(mn, s));
    mx = fmaxf(mx, __shfl_xor(mx, s));
  }
  if (lane == 0) { smn[w] = mn; smx[w] = mx; }
  __syncthreads();
  if (tid == 0) {
#pragma unroll
    for (int i = 1; i < 8; ++i) { mn = fminf(mn, smn[i]); mx = fmaxf(mx, smx[i]); }
    unsigned o0 = atomicExch(&bmn[blockIdx.x], enc_f32(mn));
    unsigned o1 = atomicExch(&bmx[blockIdx.x], enc_f32(mx));
    asm volatile("" :: "v"(o0), "v"(o1));  // both ACKs, one round trip
    lastf = (atomicAdd(&cnt[0], 1u) == NGB - 1u);
  }
  __syncthreads();
  if (!lastf) return;

  // ===== last block: global min/max reduce over slots =====
  unsigned vmn = 0xFFFFFFFFu, vmx = 0u;
  for (int i = tid; i < NGB; i += 512) {
    const unsigned a = atomicOr(&bmn[i], 0u);   // coherent device-scope read
    const unsigned b = atomicOr(&bmx[i], 0u);
    vmn = (a < vmn) ? a : vmn;
    vmx = (b > vmx) ? b : vmx;
  }
#pragma unroll
  for (int s = 1; s < 64; s <<= 1) {
    const unsigned a = (unsigned)__shfl_xor((int)vmn, s);
    const unsigned b = (unsigned)__shfl_xor((int)vmx, s);
    vmn = (a < vmn) ? a : vmn;
    vmx = (b > vmx) ? b : vmx;
  }
  if (lane == 0) { umn[w] = vmn; umx[w] = vmx; }
  __syncthreads();
  unsigned fmn = umn[0], fmx = umx[0];
#pragma unroll
  for (int i = 1; i < 8; ++i) {
    fmn = (umn[i] < fmn) ? umn[i] : fmn;
    fmx = (umx[i] > fmx) ? umx[i] : fmx;
  }
  const float lmn = dec_f32(fmn), lmx = dec_f32(fmx);
  if (tid == 255) mmf[0] = betaP[0] / (lmx - lmn);   // binv for k_zmax

  // ===== fused Newton scan for c_t, P_t (tid<64) + SArr (tid 64..191) =====
  if (tid < 64) {
    const int ln = tid;
    const float alpha = alphaP[0];
    const float sb = betaP[0] * lmn / (lmx - lmn);   // -beta*xn(xe=0)
    const float tl = (float)(ln * 32);

    float c = sqrtf(fmaf(2.0f * alpha, tl, 1.0f));
    if (fabsf(sb) > 1e-7f) {
      const float isb = 1.0f / sb;
      const float k2 = alpha * isb * isb;
      const float d0 = fmaxf(alpha + sb, 1e-8f);
#pragma unroll
      for (int it = 0; it < 4; ++it) {
        const float den = fmaxf(fmaf(sb, c, alpha), 1e-8f);
        const float T = (c - 1.0f) * isb - k2 * logf(den / d0);
        c = c - (T - tl) * den / c;
        c = fminf(fmaxf(c, 1.0f), 1e3f);
      }
    }
    if (ln == 0) c = 1.0f;

#pragma unroll
    for (int sw = 0; sw < 3; ++sw) {
      float cc = c, d = 1.0f;
#pragma unroll
      for (int j = 0; j < 32; ++j) {
        const float r = __builtin_amdgcn_rcpf(cc);
        d *= fmaf(-alpha * r, r, 1.0f);
        cc = fmaf(alpha, r, cc) + sb;
      }
      float A = d, Bv = fmaf(-d, c, cc);
#pragma unroll
      for (int o = 1; o < 64; o <<= 1) {
        const float A2 = __shfl_up(A, o);
        const float B2 = __shfl_up(Bv, o);
        if (ln >= o) { Bv = fmaf(A, B2, Bv); A *= A2; }
      }
      const float As = __shfl_up(A, 1);
      const float Bs = __shfl_up(Bv, 1);
      if (ln > 0) c = As + Bs;
    }

    float av[32];
    float cc = c, Q = 1.0f;
#pragma unroll
    for (int j = 0; j < 32; ++j) {
      cArr[ln * 32 + j] = cc;
      const float r = __builtin_amdgcn_rcpf(cc);
      const float a = fmaf(-alpha * r, r, 1.0f);
      av[j] = a; Q *= a;
      cc = fmaf(alpha, r, cc) + sb;
    }
    float Pp = Q;
#pragma unroll
    for (int o = 1; o < 64; o <<= 1) {
      const float q2 = __shfl_up(Pp, o);
      if (ln >= o) Pp *= q2;
    }
    const float Ps = __shfl_up(Pp, 1);
    float P = (ln == 0) ? 1.0f : Ps;
#pragma unroll
    for (int j = 0; j < 32; ++j) {
      pArr[ln * 32 + j] = P;
      P *= av[j];
    }
  } else if (tid < 192) {
    const int cl = tid - 64;
    float s = 0.0f;
    for (int k = 0; k < E_; ++k) s += W1[k * H_ + cl];
    SArr[cl] = s;
  }
}

// ---- K3: per-(b, 32-step segment) partial sums. tok/q preloaded into
// lanes 0-31, per-step via __shfl -> all 32 row-gathers independent. ----
__global__ __launch_bounds__(256) void k_psum(const int* __restrict__ x,
                                              const unsigned short* __restrict__ embW1,
                                              const float* __restrict__ pArr,
                                              float* __restrict__ psum) {
  const int bid = blockIdx.x;             // 1024 blocks
  const int b = bid >> 4, sq = bid & 15;
  const int wv = threadIdx.x >> 6, lane = threadIdx.x & 63;
  const int v = sq * 4 + wv;              // 0..63
  const int t0 = v * 32;
  const int col2 = lane * 2;
  int tokv = 0; float qv = 0.0f;
  if (lane < 32) {
    const int t = t0 + lane;
    tokv = x[b * L_ + t];
    qv = (t + 1 < L_) ? __builtin_amdgcn_rcpf(pArr[t + 1]) : 0.0f;
  }
  float s0 = 0.f, s1 = 0.f;
#pragma unroll
  for (int j = 0; j < 32; ++j) {
    const int tok = __shfl(tokv, j);
    const float q = __shfl(qv, j);
    const unsigned y2 = *(const unsigned*)(embW1 + (size_t)tok * H_ + col2);
    s0 = fmaf(q, __uint_as_float(y2 << 16), s0);
    s1 = fmaf(q, __uint_as_float(y2 & 0xFFFF0000u), s1);
  }
  float* p = psum + (size_t)(b * 64 + v) * H_ + col2;
  p[0] = s0; p[1] = s1;
}

// ---- K4: z-max per (b, quarter). psum cached in LDS; wmax written via
// atomicExch (ACK-consumed); last block fuses tanh + W2 matvec. ----
__global__ __launch_bounds__(1024) void k_zmax(
    const int* __restrict__ x, const unsigned short* __restrict__ embW1,
    const float* __restrict__ cArr, const float* __restrict__ pArr,
    const float* __restrict__ SArr, const float* __restrict__ psum,
    const float* __restrict__ mmf,
    float* __restrict__ wmax, unsigned* __restrict__ cnt,
    const float* __restrict__ b1, const float* __restrict__ W2,
    const float* __restrict__ b2, float* __restrict__ out) {
  __shared__ float ps[64][128];           // psum cache; reused as pooled staging
  __shared__ float zsh[16][128];
  __shared__ bool lastf;
  const int bid = blockIdx.x;             // 256 blocks
  const int b = bid >> 2, qt = bid & 3;
  const int tid = threadIdx.x;
  const int wv = tid >> 6, lane = tid & 63;
  const int v = qt * 16 + wv;             // 0..63
  const int t0 = v * 32;
  const int col2 = lane * 2;

  for (int i = tid; i < 64 * 128; i += 1024)      // cache psum[b][*][*]
    ps[i >> 7][i & 127] = psum[(size_t)(b * 64) * H_ + i];

  int tokv = 0; float qv = 0.f, cv = 0.f, pv = 0.f;
  if (lane < 32) {
    const int t = t0 + lane;
    tokv = x[b * L_ + t];
    cv = cArr[t];
    pv = pArr[t];
    qv = (t + 1 < L_) ? __builtin_amdgcn_rcpf(pArr[t + 1]) : 0.0f;
  }
  const float binv = mmf[0];
  const float S0 = SArr[col2], S1 = SArr[col2 + 1];
  __syncthreads();

  float m0 = 0.f, m1 = 0.f;               // prefix m at t0 from LDS
  for (int u = 0; u < v; ++u) { m0 += ps[u][col2]; m1 += ps[u][col2 + 1]; }

  float z0m = -3.4e38f, z1m = -3.4e38f;
#pragma unroll
  for (int j = 0; j < 32; ++j) {
    const int tok = __shfl(tokv, j);
    const float ct = __shfl(cv, j);
    const float gt = binv * __shfl(pv, j);
    const float q = __shfl(qv, j);
    const unsigned y2 = *(const unsigned*)(embW1 + (size_t)tok * H_ + col2);
    z0m = fmaxf(z0m, fmaf(-gt, m0, ct * S0));   // z uses m BEFORE adding term t
    z1m = fmaxf(z1m, fmaf(-gt, m1, ct * S1));
    m0 = fmaf(q, __uint_as_float(y2 << 16), m0);
    m1 = fmaf(q, __uint_as_float(y2 & 0xFFFF0000u), m1);
  }
  zsh[wv][col2] = z0m; zsh[wv][col2 + 1] = z1m;
  __syncthreads();
  if (tid < 128) {
    float mz = zsh[0][tid];
#pragma unroll
    for (int w2 = 1; w2 < 16; ++w2) mz = fmaxf(mz, zsh[w2][tid]);
    unsigned old = atomicExch((unsigned*)&wmax[(b * 4 + qt) * H_ + tid],
                              __float_as_uint(mz));
    asm volatile("" :: "v"(old));         // wait L2 ACK -> visible before signal
  }
  __syncthreads();
  if (tid == 0) lastf = (atomicAdd(&cnt[1], 1u) == 255u);
  __syncthreads();
  if (!lastf) return;

  // ===== fused tail: pooled = tanh(max_q wmax + b1); out = pooled@W2 + b2 =====
  for (int idx = tid; idx < B_ * H_; idx += 1024) {
    const int bb = idx >> 7, h = idx & 127;
    float mz = wmax[(bb * 4) * H_ + h];
#pragma unroll
    for (int q2 = 1; q2 < 4; ++q2) mz = fmaxf(mz, wmax[(bb * 4 + q2) * H_ + h]);
    ps[bb][h] = tanhf(mz + b1[h]);
  }
  __syncthreads();
  if (tid < B_ * C_) {
    const int bb = tid / C_, c = tid % C_;
    float s = b2[c];
#pragma unroll 8
    for (int k = 0; k < H_; ++k) s = fmaf(ps[bb][k], W2[k * C_ + c], s);
    out[tid] = s;
  }
}

extern "C" void kernel_launch(void* const* d_in, const int* in_sizes, int n_in,
                              void* d_out, int out_size, void* d_ws, size_t ws_size,
                              hipStream_t stream) {
  const int* x = (const int*)d_in[0];
  const float* emb = (const float*)d_in[1];
  const float* alpha = (const float*)d_in[2];
  const float* beta = (const float*)d_in[3];
  const float* W1 = (const float*)d_in[4];
  const float* b1 = (const float*)d_in[5];
  const float* W2 = (const float*)d_in[6];
  const float* b2 = (const float*)d_in[7];
  (void)in_sizes; (void)n_in; (void)out_size; (void)ws_size;

  char* ws = (char*)d_ws;
  unsigned* cnt = (unsigned*)ws;
  unsigned* bm = (unsigned*)(ws + 16);
  float* cArr = (float*)(ws + 8192);
  float* pArr = (float*)(ws + 16384);
  float* SArr = (float*)(ws + 24576);
  float* mmf = (float*)(ws + 25600);
  unsigned* bmn = (unsigned*)(ws + 32768);
  unsigned* bmx = (unsigned*)(ws + 36864);
  unsigned short* embW1 = (unsigned short*)(ws + 65536);
  unsigned short* w1t = (unsigned short*)(ws + 12865536);  // aliases psum (safe)
  float* psum = (float*)(ws + 12865536);
  float* wmax = (float*)(ws + 14962688);

  k_init<<<1, 512, 0, stream>>>(cnt, bm);
  k_bitmap<<<(B_ * L_) / 256, 256, 0, stream>>>(x, bm, W1, w1t);
  k_gemm<<<NGB, 512, 0, stream>>>(emb, W1, bm, bmn, bmx, embW1, cnt, w1t,
                                  alpha, beta, cArr, pArr, SArr, mmf);
  k_psum<<<1024, 256, 0, stream>>>(x, embW1, pArr, psum);
  k_zmax<<<256, 1024, 0, stream>>>(x, embW1, cArr, pArr, SArr, psum, mmf,
                                   wmax, cnt, b1, W2, b2, (float*)d_out);
}